// Round 15
// baseline (208.036 us; speedup 1.0000x reference)
//
#include <hip/hip_runtime.h>
#include <hip/hip_bf16.h>
#include <cstddef>

// Shapes: B=16, M=128, L=512, HID=256, H=4, DH=64, LAYERS=2
#define Bsz 16
#define Msz 128
#define Lsz 512
#define HIDs 256

typedef __attribute__((ext_vector_type(4))) float f32x4;
typedef __attribute__((ext_vector_type(8))) __bf16 bf16x8;
typedef __attribute__((ext_vector_type(8))) unsigned short ushort8;

#define CHEB_K 12
#define PI_F 3.14159265358979323846f

static __device__ inline unsigned short f2bf(float f) {
    __hip_bfloat16 h = __float2bfloat16(f);
    return *(unsigned short*)&h;
}
static __device__ inline float bf2f(unsigned short u) {
    return __builtin_bit_cast(float, (unsigned)u << 16);
}
static __device__ inline void gload16(const ushort* g, ushort* l) {
    __builtin_amdgcn_global_load_lds(
        (const __attribute__((address_space(1))) void*)g,
        (__attribute__((address_space(3))) void*)l, 16, 0, 0);
}

// ---------------------------------------------------------------------------
// Grid-fused prep: [0,1920) cvt/repack (Wqkv q-rows pre-scaled by 0.125);
// [1920,6016) tokenizer denominators (cd computed inline per block);
// [6016] scaled bqkv copy.
// ---------------------------------------------------------------------------
__global__ __launch_bounds__(256) void prep_kernel(
    const float* __restrict__ ts_emb, const float* __restrict__ ct_emb,
    const float* __restrict__ ct_W, const float* __restrict__ fW0,
    const float* __restrict__ fW1, const float* __restrict__ fW2,
    const float* __restrict__ Wqkv, const float* __restrict__ Wo,
    const float* __restrict__ W1, const float* __restrict__ W2,
    ushort* __restrict__ Xcat, ushort* __restrict__ Wcat,
    ushort* __restrict__ cebin, ushort* __restrict__ wct,
    ushort* __restrict__ wf2, ushort* __restrict__ wqkv,
    ushort* __restrict__ wo, ushort* __restrict__ w1, ushort* __restrict__ w2,
    const float* __restrict__ ct_t, const float* __restrict__ ts_t,
    const float* __restrict__ kp, ushort* __restrict__ invW,
    const float* __restrict__ bqkv, float* __restrict__ bqs)
{
    const int bid = blockIdx.x;
    const int tid = threadIdx.x;

    if (bid < 1920) {
        const unsigned u = bid * 256u + tid;
        const float* src; ushort* dst; unsigned rel;
        float sc = 1.f;
        if (u < 262144u) {
            rel = u; src = ts_emb;
            dst = Xcat + ((size_t)(rel >> 5) * 512 + 256 + (rel & 31) * 8);
        } else if (u < 327680u) { rel = u - 262144u; src = ct_emb; dst = cebin + (size_t)rel * 8; }
        else if (u < 335872u) { rel = u - 327680u; src = ct_W; dst = wct + (size_t)rel * 8; }
        else if (u < 344064u) { rel = u - 335872u; src = fW0;
            dst = Wcat + ((size_t)(rel >> 5) * 512 + (rel & 31) * 8); }
        else if (u < 352256u) { rel = u - 344064u; src = fW1;
            dst = Wcat + ((size_t)(rel >> 5) * 512 + 256 + (rel & 31) * 8); }
        else if (u < 360448u) { rel = u - 352256u; src = fW2; dst = wf2 + (size_t)rel * 8; }
        else if (u < 409600u) { rel = u - 360448u; src = Wqkv; dst = wqkv + (size_t)rel * 8;
            if (((rel >> 5) % 768) < 256) sc = 0.125f; }   // q rows pre-scaled
        else if (u < 425984u) { rel = u - 409600u; src = Wo;  dst = wo + (size_t)rel * 8; }
        else if (u < 458752u) { rel = u - 425984u; src = W1;  dst = w1 + (size_t)rel * 8; }
        else                  { rel = u - 458752u; src = W2;  dst = w2 + (size_t)rel * 8; }
        float4 a = ((const float4*)src)[(size_t)rel * 2];
        float4 b = ((const float4*)src)[(size_t)rel * 2 + 1];
        ushort8 o;
        o[0] = f2bf(a.x * sc); o[1] = f2bf(a.y * sc); o[2] = f2bf(a.z * sc); o[3] = f2bf(a.w * sc);
        o[4] = f2bf(b.x * sc); o[5] = f2bf(b.y * sc); o[6] = f2bf(b.z * sc); o[7] = f2bf(b.w * sc);
        *(ushort8*)dst = o;
    } else if (bid < 6016) {
        // ---- denominators, cd computed inline ----
        __shared__ float cd[3][CHEB_K];
        __shared__ float costab[CHEB_K][32];
        __shared__ float xq[32];
        #pragma unroll
        for (int i = 0; i < 2; i++) {
            int idx = i * 256 + tid;
            if (idx < CHEB_K * 32) {
                int k = idx >> 5, q = idx & 31;
                costab[k][q] = __cosf((float)k * ((q + 0.5f) * (PI_F / 32.f)));
            }
        }
        if (tid < 32) xq[tid] = 0.5f * (1.f + __cosf((tid + 0.5f) * (PI_F / 32.f)));
        __syncthreads();
        if (tid < 192) {
            const int d = tid & 63, s1 = tid >> 6;
            float p = kp[d];
            float a = fmaxf(p, 0.f) + log1pf(__expf(-fabsf(p)));
            const float u = (float)(s1 + 1) * a;
            float f[32];
            #pragma unroll
            for (int q = 0; q < 32; q++) f[q] = __expf(-u * xq[q]);
            #pragma unroll
            for (int k = 0; k < CHEB_K; k++) {
                float sum = 0.f;
                #pragma unroll
                for (int q = 0; q < 32; q++) sum = fmaf(f[q], costab[k][q], sum);
                float c = sum * ((k == 0 ? 1.f : 2.f) / 32.f);
                #pragma unroll
                for (int o = 1; o <= 32; o <<= 1) c += __shfl_xor(c, o, 64);
                if (d == 0) cd[s1][k] = c;
            }
        }
        __syncthreads();

        const unsigned G = (bid - 1920) * 256u + tid;
        const int b = G >> 16;
        const int n = (G >> 7) & 511;
        const int m = G & 127;

        float x = ct_t[b * Msz + m] - ts_t[b * Lsz + n];
        x = x * x;
        const float xi = 2.f * x - 1.f;
        const float xi2 = 2.f * xi;

        float t0 = 1.f, t1 = xi;
        float a1 = cd[0][0] + cd[0][1] * xi;
        float a2 = cd[1][0] + cd[1][1] * xi;
        float a3 = cd[2][0] + cd[2][1] * xi;
        #pragma unroll
        for (int k = 2; k < CHEB_K; k++) {
            float tn = fmaf(xi2, t1, -t0);
            a1 = fmaf(cd[0][k], tn, a1);
            a2 = fmaf(cd[1][k], tn, a2);
            a3 = fmaf(cd[2][k], tn, a3);
            t0 = t1; t1 = tn;
        }
        const size_t base = ((size_t)b * 3 * Lsz + n) * Msz + m;
        invW[base]                         = f2bf(1.f / a1);
        invW[base + (size_t)Lsz * Msz]     = f2bf(1.f / a2);
        invW[base + (size_t)2 * Lsz * Msz] = f2bf(1.f / a3);
    } else {
        #pragma unroll
        for (int i = 0; i < 6; i++) {
            int idx = i * 256 + tid;   // 1536 = 2*768
            int c = idx % 768;
            bqs[idx] = bqkv[idx] * ((c < 256) ? 0.125f : 1.f);
        }
    }
}

// ---------------------------------------------------------------------------
// MFMA bf16 GEMM, double-buffered LDS staging, 256 threads, 64x128 tile.
// ---------------------------------------------------------------------------
__global__ __launch_bounds__(256) void gemm_mfma_kernel(
    const ushort* __restrict__ X, const ushort* __restrict__ W,
    const float* __restrict__ bias, const float* __restrict__ bias2,
    ushort* __restrict__ Yb, int NR, int K, int OUT, int act)
{
    __shared__ ushort As[2][64 * 64];
    __shared__ ushort Bs[2][128 * 64];

    const int nbx = OUT >> 7;
    const int bx = blockIdx.x % nbx;
    const int by = blockIdx.x / nbx;
    const int r0 = by << 6, o0 = bx << 7;
    const int tid = threadIdx.x;
    const int w = tid >> 6;
    const int lane = tid & 63;
    const int wr = w >> 1, wc = w & 1;
    const int lr = lane & 15, lg = lane >> 4;

    const int grow = lane >> 3;
    const int gchunk = (lane & 7) ^ grow;

    unsigned aoff[2][2], boff[4][2];
    #pragma unroll
    for (int f = 0; f < 2; f++) {
        unsigned cc = (unsigned)((lg + 4 * f) ^ (lr & 7)) * 16u;
        #pragma unroll
        for (int m = 0; m < 2; m++)
            aoff[m][f] = (unsigned)(wr * 32 + m * 16 + lr) * 128u + cc;
        #pragma unroll
        for (int n = 0; n < 4; n++)
            boff[n][f] = (unsigned)(wc * 64 + n * 16 + lr) * 128u + cc;
    }

    f32x4 acc[2][4];
    #pragma unroll
    for (int m = 0; m < 2; m++)
        #pragma unroll
        for (int n = 0; n < 4; n++) acc[m][n] = (f32x4){0.f, 0.f, 0.f, 0.f};

    const int nk = K >> 6;

    auto stage = [&](int buf, int ks) {
        const int k0 = ks << 6;
        #pragma unroll
        for (int i = 0; i < 2; i++) {
            int row = w * 16 + i * 8 + grow;
            gload16(X + (size_t)(r0 + row) * K + k0 + gchunk * 8,
                    &As[buf][(w * 16 + i * 8) * 64]);
        }
        #pragma unroll
        for (int i = 0; i < 4; i++) {
            int row = w * 32 + i * 8 + grow;
            gload16(W + (size_t)(o0 + row) * K + k0 + gchunk * 8,
                    &Bs[buf][(w * 32 + i * 8) * 64]);
        }
    };

    stage(0, 0);
    __syncthreads();
    int cur = 0;
    for (int ks = 0; ks < nk; ks++) {
        if (ks + 1 < nk) stage(cur ^ 1, ks + 1);
        const char* Ab = (const char*)As[cur];
        const char* Bb = (const char*)Bs[cur];
        #pragma unroll
        for (int f = 0; f < 2; f++) {
            bf16x8 av[2], bv[4];
            #pragma unroll
            for (int m = 0; m < 2; m++)
                av[m] = *(const bf16x8*)(Ab + aoff[m][f]);
            #pragma unroll
            for (int n = 0; n < 4; n++)
                bv[n] = *(const bf16x8*)(Bb + boff[n][f]);
            #pragma unroll
            for (int m = 0; m < 2; m++)
                #pragma unroll
                for (int n = 0; n < 4; n++)
                    acc[m][n] = __builtin_amdgcn_mfma_f32_16x16x32_bf16(
                        av[m], bv[n], acc[m][n], 0, 0, 0);
        }
        __syncthreads();
        cur ^= 1;
    }

    const int ocol0 = o0 + wc * 64;
    float bn[4];
    #pragma unroll
    for (int n = 0; n < 4; n++) {
        int o = ocol0 + n * 16 + lr;
        bn[n] = bias[o] + (bias2 ? bias2[o] : 0.f);
    }

    #pragma unroll
    for (int m = 0; m < 2; m++) {
        #pragma unroll
        for (int p = 0; p < 4; p++) {
            int r = r0 + wr * 32 + m * 16 + 4 * lg + p;
            size_t rb = (size_t)r * OUT;
            #pragma unroll
            for (int n = 0; n < 4; n++) {
                int o = ocol0 + n * 16 + lr;
                float v = acc[m][n][p] + bn[n];
                if (act == 1)      v = (v > 0.f) ? v : (__expf(v) - 1.f);
                else if (act == 2) v = 0.5f * v * (1.f + erff(v * 0.70710678118654752f));
                Yb[rb + o] = f2bf(v);
            }
        }
    }
}

// ---------------------------------------------------------------------------
// Fused GEMM + residual(bf16) + LayerNorm (+ optional pred head).
// 512 threads = 8 waves (2 row-groups x 4 col-slices), 32 rows x 256 cols.
// ---------------------------------------------------------------------------
__global__ __launch_bounds__(512) void gemm_ln_kernel(
    const ushort* __restrict__ X, const ushort* __restrict__ W,
    const float* __restrict__ bias, const ushort* __restrict__ add,
    int addS, int addO,
    const float* __restrict__ lng, const float* __restrict__ lnb,
    ushort* __restrict__ Xb,
    const float* __restrict__ predW, const float* __restrict__ predb,
    float* __restrict__ pout, int K)
{
    __shared__ ushort As[2][32 * 64];
    __shared__ ushort Bs[2][256 * 64];
    __shared__ float redA[32][4];
    __shared__ float redB[32][4];

    const int r0 = blockIdx.x << 5;
    const int tid = threadIdx.x;
    const int w = tid >> 6;
    const int lane = tid & 63;
    const int lr = lane & 15, lg = lane >> 4;
    const int wg = w >> 2;
    const int ws = w & 3;
    const int grow = lane >> 3;
    const int gchunk = (lane & 7) ^ grow;

    unsigned aoff[2], boff[4][2];
    #pragma unroll
    for (int f = 0; f < 2; f++) {
        unsigned cc = (unsigned)((lg + 4 * f) ^ (lr & 7)) * 16u;
        aoff[f] = (unsigned)(wg * 16 + lr) * 128u + cc;
        #pragma unroll
        for (int n = 0; n < 4; n++)
            boff[n][f] = (unsigned)(ws * 64 + n * 16 + lr) * 128u + cc;
    }

    f32x4 acc[4];
    #pragma unroll
    for (int n = 0; n < 4; n++) acc[n] = (f32x4){0.f, 0.f, 0.f, 0.f};

    const int nk = K >> 6;

    auto stage = [&](int buf, int ks) {
        const int k0 = ks << 6;
        if (w < 4)
            gload16(X + (size_t)(r0 + w * 8 + grow) * K + k0 + gchunk * 8,
                    &As[buf][(w * 8) * 64]);
        #pragma unroll
        for (int i = 0; i < 4; i++) {
            gload16(W + (size_t)(w * 32 + i * 8 + grow) * K + k0 + gchunk * 8,
                    &Bs[buf][(w * 32 + i * 8) * 64]);
        }
    };

    stage(0, 0);
    __syncthreads();
    int cur = 0;
    for (int ks = 0; ks < nk; ks++) {
        if (ks + 1 < nk) stage(cur ^ 1, ks + 1);
        const char* Ab = (const char*)As[cur];
        const char* Bb = (const char*)Bs[cur];
        #pragma unroll
        for (int f = 0; f < 2; f++) {
            bf16x8 av = *(const bf16x8*)(Ab + aoff[f]);
            #pragma unroll
            for (int n = 0; n < 4; n++) {
                bf16x8 bv = *(const bf16x8*)(Bb + boff[n][f]);
                acc[n] = __builtin_amdgcn_mfma_f32_16x16x32_bf16(
                    av, bv, acc[n], 0, 0, 0);
            }
        }
        __syncthreads();
        cur ^= 1;
    }

    const int col0 = ws * 64;
    float bn[4], gv[4], bv2[4], pwv[4];
    #pragma unroll
    for (int n = 0; n < 4; n++) {
        int o = col0 + n * 16 + lr;
        bn[n] = bias[o];
        gv[n] = lng[o];
        bv2[n] = lnb[o];
        pwv[n] = predW ? predW[o] : 0.f;
    }
    #pragma unroll
    for (int p = 0; p < 4; p++) {
        size_t ra = (size_t)(r0 + wg * 16 + 4 * lg + p) * addS + addO;
        #pragma unroll
        for (int n = 0; n < 4; n++)
            acc[n][p] += bn[n] + bf2f(add[ra + col0 + n * 16 + lr]);
    }

    #pragma unroll
    for (int p = 0; p < 4; p++) {
        float s = acc[0][p] + acc[1][p] + acc[2][p] + acc[3][p];
        #pragma unroll
        for (int o = 1; o <= 8; o <<= 1) s += __shfl_xor(s, o);
        if (lr == 0) redA[wg * 16 + 4 * lg + p][ws] = s;
    }
    __syncthreads();
    float mu[4];
    #pragma unroll
    for (int p = 0; p < 4; p++) {
        int row = wg * 16 + 4 * lg + p;
        mu[p] = (redA[row][0] + redA[row][1] + redA[row][2] + redA[row][3]) * (1.f / 256.f);
    }

    #pragma unroll
    for (int p = 0; p < 4; p++) {
        float q = 0.f;
        #pragma unroll
        for (int n = 0; n < 4; n++) {
            float dl = acc[n][p] - mu[p];
            q = fmaf(dl, dl, q);
        }
        #pragma unroll
        for (int o = 1; o <= 8; o <<= 1) q += __shfl_xor(q, o);
        if (lr == 0) redB[wg * 16 + 4 * lg + p][ws] = q;
    }
    __syncthreads();

    #pragma unroll
    for (int p = 0; p < 4; p++) {
        int row = wg * 16 + 4 * lg + p;
        float var = (redB[row][0] + redB[row][1] + redB[row][2] + redB[row][3]) * (1.f / 256.f);
        float rsig = rsqrtf(var + 1e-5f);
        size_t rb = (size_t)(r0 + row) * 256;
        float pd = 0.f;
        #pragma unroll
        for (int n = 0; n < 4; n++) {
            int o = col0 + n * 16 + lr;
            float xn = (acc[n][p] - mu[p]) * rsig * gv[n] + bv2[n];
            if (Xb) Xb[rb + o] = f2bf(xn);
            pd = fmaf(xn, pwv[n], pd);
        }
        if (predW) {
            #pragma unroll
            for (int o = 1; o <= 8; o <<= 1) pd += __shfl_xor(pd, o);
            if (lr == 0) redA[row][ws] = pd;
        }
    }
    if (predW) {
        __syncthreads();
        if (tid < 32)
            pout[r0 + tid] = redA[tid][0] + redA[tid][1] + redA[tid][2]
                           + redA[tid][3] + predb[0];
    }
}

// ---------------------------------------------------------------------------
// Grid-fused tokenizer: [0,384) tok3 MFMA (cl computed inline);
// [384,400) scale-0 broadcast.
// ---------------------------------------------------------------------------
__global__ __launch_bounds__(256) void tokmix_kernel(
    const float* __restrict__ ct_t, const float* __restrict__ ts_t,
    const ushort* __restrict__ ceb, const ushort* __restrict__ invW,
    const float* __restrict__ kp, ushort* __restrict__ Xcat)
{
    const int bid = blockIdx.x;
    const int tid = threadIdx.x;

    if (bid < 384) {
        const int nt = bid & 7;
        const int s1 = (bid >> 3) % 3;
        const int b  = bid / 24;
        const int w = tid >> 6, lane = tid & 63, g = lane >> 4, r = lane & 15;

        __shared__ ushort ceT[64][136];
        __shared__ float  cl[CHEB_K][64];
        __shared__ float  cts[128];
        __shared__ float  costab[CHEB_K][32];
        __shared__ float  xq[32];

        #pragma unroll
        for (int i = 0; i < 8; i++) {
            int idx = i * 256 + tid;
            int m = idx >> 4, d4 = (idx & 15) << 2;
            const ushort* gp = ceb + (((size_t)b * 128 + m) << 8) + (s1 + 1) * 64 + d4;
            ushort4 v = *(const ushort4*)gp;
            ceT[d4 + 0][m] = v.x; ceT[d4 + 1][m] = v.y;
            ceT[d4 + 2][m] = v.z; ceT[d4 + 3][m] = v.w;
        }
        #pragma unroll
        for (int i = 0; i < 2; i++) {
            int idx = i * 256 + tid;
            if (idx < CHEB_K * 32) {
                int k = idx >> 5, q = idx & 31;
                costab[k][q] = __cosf((float)k * ((q + 0.5f) * (PI_F / 32.f)));
            }
        }
        if (tid < 32) xq[tid] = 0.5f * (1.f + __cosf((tid + 0.5f) * (PI_F / 32.f)));
        if (tid < 128) cts[tid] = ct_t[b * 128 + tid];
        __syncthreads();

        if (tid < 64) {
            float p = kp[tid];
            float a = fmaxf(p, 0.f) + log1pf(__expf(-fabsf(p)));
            const float u = (float)(s1 + 1) * a;
            float f[32];
            #pragma unroll
            for (int q = 0; q < 32; q++) f[q] = __expf(-u * xq[q]);
            #pragma unroll
            for (int k = 0; k < CHEB_K; k++) {
                float sum = 0.f;
                #pragma unroll
                for (int q = 0; q < 32; q++) sum = fmaf(f[q], costab[k][q], sum);
                cl[k][tid] = sum * ((k == 0 ? 1.f : 2.f) / 32.f);
            }
        }

        const int nrow = nt * 64 + w * 16 + r;
        const float tsn = ts_t[b * 512 + nrow];

        float xi2v[4][8], Ta[4][8], Tb[4][8];
        #pragma unroll
        for (int t4 = 0; t4 < 4; t4++) {
            int m0 = 8 * g + 32 * t4;
            ushort8 iv = *(const ushort8*)&invW[((((size_t)b * 3 + s1) * 512 + nrow) << 7) + m0];
            #pragma unroll
            for (int j = 0; j < 8; j++) {
                float dfx = cts[m0 + j] - tsn;
                float x = dfx * dfx;
                float xi = 2.f * x - 1.f;
                float w0 = bf2f(iv[j]);
                xi2v[t4][j] = 2.f * xi;
                Ta[t4][j] = w0;
                Tb[t4][j] = w0 * xi;
            }
        }

        bf16x8 cef[4][4];
        #pragma unroll
        for (int db = 0; db < 4; db++)
            #pragma unroll
            for (int t4 = 0; t4 < 4; t4++)
                cef[db][t4] = *(const bf16x8*)&ceT[db * 16 + r][8 * g + 32 * t4];

        __syncthreads();   // cl ready

        f32x4 acc[4];
        #pragma unroll
        for (int db = 0; db < 4; db++) acc[db] = (f32x4){0.f, 0.f, 0.f, 0.f};

        #pragma unroll
        for (int k = 0; k < CHEB_K; k++) {
            if (k >= 2) {
                #pragma unroll
                for (int t4 = 0; t4 < 4; t4++)
                    #pragma unroll
                    for (int j = 0; j < 8; j++) {
                        if (k & 1) Tb[t4][j] = fmaf(xi2v[t4][j], Ta[t4][j], -Tb[t4][j]);
                        else       Ta[t4][j] = fmaf(xi2v[t4][j], Tb[t4][j], -Ta[t4][j]);
                    }
            }
            bf16x8 af[4];
            #pragma unroll
            for (int t4 = 0; t4 < 4; t4++) {
                ushort8 u;
                #pragma unroll
                for (int j = 0; j < 8; j++)
                    u[j] = f2bf((k & 1) ? Tb[t4][j] : Ta[t4][j]);
                af[t4] = __builtin_bit_cast(bf16x8, u);
            }
            #pragma unroll
            for (int db = 0; db < 4; db++) {
                f32x4 gk = (f32x4){0.f, 0.f, 0.f, 0.f};
                #pragma unroll
                for (int t4 = 0; t4 < 4; t4++)
                    gk = __builtin_amdgcn_mfma_f32_16x16x32_bf16(af[t4], cef[db][t4], gk, 0, 0, 0);
                float ck = cl[k][db * 16 + r];
                #pragma unroll
                for (int p = 0; p < 4; p++) acc[db][p] = fmaf(ck, gk[p], acc[db][p]);
            }
        }

        #pragma unroll
        for (int db = 0; db < 4; db++)
            #pragma unroll
            for (int p = 0; p < 4; p++) {
                int n_out = nt * 64 + w * 16 + 4 * g + p;
                Xcat[((size_t)b * 512 + n_out) * 512 + (s1 + 1) * 64 + db * 16 + r] =
                    f2bf(acc[db][p]);
            }
    } else {
        const int b = bid - 384;
        const int d = tid & 63, q = tid >> 6;
        float s = 0.f;
        #pragma unroll 8
        for (int i = 0; i < 32; i++) {
            int m = q * 32 + i;
            s += bf2f(ceb[(((size_t)b * 128 + m) << 8) + d]);
        }
        __shared__ float red0[4][64];
        __shared__ ushort row0[64];
        red0[q][d] = s;
        __syncthreads();
        if (tid < 64)
            row0[tid] = f2bf((red0[0][tid] + red0[1][tid] + red0[2][tid] + red0[3][tid])
                             * (1.f / 64.f));
        __syncthreads();
        #pragma unroll
        for (int i = 0; i < 16; i++) {
            int idx = i * 256 + tid;
            int n = idx >> 3, j = idx & 7;
            *(ushort8*)&Xcat[((size_t)b * 512 + n) * 512 + j * 8] =
                *(const ushort8*)&row0[j * 8];
        }
    }
}

// ---------------------------------------------------------------------------
// MFMA bf16 flash attention (q pre-scaled by 0.125 upstream).
// 256 threads, 128-key chunks, single LDS buffer + register prefetch,
// setprio around MFMA clusters, bf16 P in LDS, defer-max (THR=8).
// Grid = B*H*8 = 512.
// ---------------------------------------------------------------------------
__global__ __launch_bounds__(256) void attn_mfma_kernel(
    const ushort* __restrict__ qkv, ushort* __restrict__ Ob)
{
    const int bid = blockIdx.x;
    const int qt = bid & 7;
    const int h  = (bid >> 3) & 3;
    const int b  = bid >> 5;
    const int t  = threadIdx.x;
    const int w  = t >> 6;
    const int lane = t & 63;
    const int g = lane >> 4;
    const int r = lane & 15;

    __shared__ ushort Ks[128][72];
    __shared__ ushort Vt[64][136];     // [d][k]
    __shared__ ushort Pb[4][16][136];  // bf16 P

    const ushort* base = qkv + (size_t)b * Lsz * 768;
    const int q0 = qt * 64 + w * 16;

    bf16x8 qf[2];
    {
        const ushort* qp = base + (size_t)(q0 + r) * 768 + h * 64 + 8 * g;
        qf[0] = __builtin_bit_cast(bf16x8, *(const ushort8*)qp);
        qf[1] = __builtin_bit_cast(bf16x8, *(const ushort8*)(qp + 32));
    }

    f32x4 Ofr[4];
    #pragma unroll
    for (int dblk = 0; dblk < 4; dblk++) Ofr[dblk] = (f32x4){0.f, 0.f, 0.f, 0.f};
    float m_run[4] = {-1e30f, -1e30f, -1e30f, -1e30f};
    float l_run[4] = {0.f, 0.f, 0.f, 0.f};

    const int srow = t >> 1;        // 0..127
    const int sseg = t & 1;         // 0..1  (32 ushorts each)

    ushort8 pk[4], pv[4];
    auto gload_chunk = [&](int c) {
        const ushort* kr = base + (size_t)(c * 128 + srow) * 768 + 256 + h * 64 + sseg * 32;
        #pragma unroll
        for (int i = 0; i < 4; i++) {
            pk[i] = *(const ushort8*)(kr + 8 * i);
            pv[i] = *(const ushort8*)(kr + 256 + 8 * i);
        }
    };
    auto write_chunk = [&]() {
        #pragma unroll
        for (int i = 0; i < 4; i++) {
            *(ushort8*)&Ks[srow][sseg * 32 + 8 * i] = pk[i];
            #pragma unroll
            for (int j = 0; j < 8; j++)
                Vt[sseg * 32 + 8 * i + j][srow] = pv[i][j];
        }
    };

    gload_chunk(0);
    write_chunk();
    __syncthreads();

    for (int c = 0; c < 4; c++) {
        if (c < 3) gload_chunk(c + 1);   // loads in flight over compute

        // ---- S = Q K^T (q pre-scaled) ----
        f32x4 sfr[8];
        __builtin_amdgcn_s_setprio(1);
        #pragma unroll
        for (int s = 0; s < 8; s++) {
            f32x4 a2 = (f32x4){0.f, 0.f, 0.f, 0.f};
            #pragma unroll
            for (int f = 0; f < 2; f++) {
                bf16x8 kf = *(const bf16x8*)&Ks[s * 16 + r][8 * g + 32 * f];
                a2 = __builtin_amdgcn_mfma_f32_16x16x32_bf16(qf[f], kf, a2, 0, 0, 0);
            }
            sfr[s] = a2;
        }
        __builtin_amdgcn_s_setprio(0);

        // ---- online softmax with defer-max (T13, THR=8) ----
        #pragma unroll
        for (int p = 0; p < 4; p++) {
            float rm = sfr[0][p];
            #pragma unroll
            for (int s = 1; s < 8; s++) rm = fmaxf(rm, sfr[s][p]);
            #pragma unroll
            for (int o = 1; o <= 8; o <<= 1) rm = fmaxf(rm, __shfl_xor(rm, o));
            if (__any(rm > m_run[p] + 8.f)) {
                float mnew = fmaxf(m_run[p], rm);
                float sc = __expf(m_run[p] - mnew);
                m_run[p] = mnew;
                l_run[p] *= sc;
                #pragma unroll
                for (int dblk = 0; dblk < 4; dblk++) Ofr[dblk][p] *= sc;
            }
            float rs = 0.f;
            #pragma unroll
            for (int s = 0; s < 8; s++) {
                float pvx = __expf(sfr[s][p] - m_run[p]);
                Pb[w][4 * g + p][s * 16 + r] = f2bf(pvx);
                rs += pvx;
            }
            #pragma unroll
            for (int o = 1; o <= 8; o <<= 1) rs += __shfl_xor(rs, o);
            l_run[p] += rs;
        }

        __asm__ volatile("s_waitcnt lgkmcnt(0)" ::: "memory");

        // ---- O += P @ V  (P A-frags read directly as bf16x8) ----
        #pragma unroll
        for (int ks2 = 0; ks2 < 4; ks2++) {
            bf16x8 pa = *(const bf16x8*)&Pb[w][r][8 * g + 32 * ks2];
            __builtin_amdgcn_s_setprio(1);
            #pragma unroll
            for (int dblk = 0; dblk < 4; dblk++) {
                bf16x8 vb = *(const bf16x8*)&Vt[dblk * 16 + r][32 * ks2 + 8 * g];
                Ofr[dblk] = __builtin_amdgcn_mfma_f32_16x16x32_bf16(
                    pa, vb, Ofr[dblk], 0, 0, 0);
            }
            __builtin_amdgcn_s_setprio(0);
        }

        __syncthreads();                 // all waves done reading Ks/Vt
        if (c < 3) {
            write_chunk();
            __syncthreads();             // writes visible
        }
    }

    #pragma unroll
    for (int dblk = 0; dblk < 4; dblk++) {
        #pragma unroll
        for (int p = 0; p < 4; p++) {
            int row = q0 + 4 * g + p;
            Ob[(size_t)(b * Lsz + row) * HIDs + h * 64 + dblk * 16 + r] =
                f2bf(Ofr[dblk][p] / l_run[p]);
        }
    }
}

// ---------------------------------------------------------------------------
extern "C" void kernel_launch(void* const* d_in, const int* in_sizes, int n_in,
                              void* d_out, int out_size, void* d_ws, size_t ws_size,
                              hipStream_t stream)
{
    (void)in_sizes; (void)n_in; (void)out_size; (void)ws_size;

    const float* ct_t   = (const float*)d_in[0];
    const float* ts_t   = (const float*)d_in[1];
    const float* ct_emb = (const float*)d_in[2];
    const float* ts_emb = (const float*)d_in[3];
    const float* kp     = (const float*)d_in[4];
    const float* ct_W   = (const float*)d_in[5];
    const float* ct_b   = (const float*)d_in[6];
    const float* fW0    = (const float*)d_in[7];
    const float* fb0    = (const float*)d_in[8];
    const float* fW1    = (const float*)d_in[9];
    const float* fb1    = (const float*)d_in[10];
    const float* fW2    = (const float*)d_in[11];
    const float* fb2    = (const float*)d_in[12];
    const float* f_ln_g = (const float*)d_in[13];
    const float* f_ln_b = (const float*)d_in[14];
    const float* Wqkv   = (const float*)d_in[15];
    const float* bqkv   = (const float*)d_in[16];
    const float* Wo     = (const float*)d_in[17];
    const float* bo     = (const float*)d_in[18];
    const float* W1     = (const float*)d_in[19];
    const float* b1     = (const float*)d_in[20];
    const float* W2     = (const float*)d_in[21];
    const float* b2     = (const float*)d_in[22];
    const float* ln1_g  = (const float*)d_in[23];
    const float* ln1_b  = (const float*)d_in[24];
    const float* ln2_g  = (const float*)d_in[25];
    const float* ln2_b  = (const float*)d_in[26];
    const float* pred_W = (const float*)d_in[27];
    const float* pred_b = (const float*)d_in[28];

    // ---- workspace layout (ushort units unless noted) ----
    ushort* wsb = (ushort*)d_ws;
    ushort* invW  = wsb;                    // [0, 12582912)
    ushort* auxbf = wsb;                    //   reuse after tokmix
    ushort* qkvbf = wsb;                    //   reuse
    ushort* ff1bf = wsb;                    //   reuse
    ushort* Xcat  = wsb + 12582912;         // 4,194,304  [8192][512]
    ushort* Wcat  = wsb + 16777216;         // 131,072
    ushort* cebin = wsb + 16908288;         // 524,288
    ushort* cebout= wsb + 17432576;         // 524,288
    ushort* wct   = wsb + 17956864;         // 65,536
    ushort* wf2   = wsb + 18022400;         // 65,536
    ushort* wqkv  = wsb + 18087936;         // 393,216
    ushort* wo    = wsb + 18481152;         // 131,072
    ushort* w1    = wsb + 18612224;         // 262,144
    ushort* w2    = wsb + 18874368;         // 262,144 -> ends 19,136,512
    ushort* xbf   = wsb + 19136512;         // 2,097,152
    ushort* obf   = wsb + 21233664;         // 2,097,152 -> ends 23,330,816
    float*  wsf   = (float*)d_ws;
    float*  bqs   = wsf + 11665408;         // 1,536 fl

    const int NRts = Bsz * Lsz;  // 8192
    const int NRct = Bsz * Msz;  // 2048
    auto grid = [](int nr, int out) { return dim3((unsigned)((nr >> 6) * (out >> 7))); };

    // --- prep: cvt + denom3(inline cd) + bq scale grid-fused ---
    prep_kernel<<<dim3(1920 + 4096 + 1), 256, 0, stream>>>(
        ts_emb, ct_emb, ct_W, fW0, fW1, fW2, Wqkv, Wo, W1, W2,
        Xcat, Wcat, cebin, wct, wf2, wqkv, wo, w1, w2,
        ct_t, ts_t, kp, invW, bqkv, bqs);

    // --- tokenizer ---
    gemm_mfma_kernel<<<grid(NRct, 256), 256, 0, stream>>>(
        cebin, wct, ct_b, nullptr, cebout, NRct, 256, 256, 0);
    tokmix_kernel<<<dim3(400), 256, 0, stream>>>(ct_t, ts_t, cebout, invW, kp, Xcat);

    // --- fusion: aux = ELU(Xcat@Wcat + fb0+fb1); x = LN(aux@fW2^T + fb2 + ts_emb) ---
    gemm_mfma_kernel<<<grid(NRts, 256), 256, 0, stream>>>(
        Xcat, Wcat, fb0, fb1, auxbf, NRts, 512, 256, 1);
    gemm_ln_kernel<<<dim3(NRts / 32), 512, 0, stream>>>(
        auxbf, wf2, fb2, Xcat, 512, 256, f_ln_g, f_ln_b, xbf,
        nullptr, nullptr, nullptr, 256);

    // --- transformer layers ---
    for (int l = 0; l < 2; l++) {
        gemm_mfma_kernel<<<grid(NRts, 768), 256, 0, stream>>>(
            xbf, wqkv + (size_t)l * 196608, bqs + l * 768, nullptr,
            qkvbf, NRts, 256, 768, 0);
        attn_mfma_kernel<<<dim3(512), 256, 0, stream>>>(qkvbf, obf);
        gemm_ln_kernel<<<dim3(NRts / 32), 512, 0, stream>>>(
            obf, wo + (size_t)l * 65536, bo + l * 256, xbf, 256, 0,
            ln1_g + l * 256, ln1_b + l * 256, xbf,
            nullptr, nullptr, nullptr, 256);
        gemm_mfma_kernel<<<grid(NRts, 512), 256, 0, stream>>>(
            xbf, w1 + (size_t)l * 131072, b1 + l * 512, nullptr,
            ff1bf, NRts, 256, 512, 2);
        if (l == 0) {
            gemm_ln_kernel<<<dim3(NRts / 32), 512, 0, stream>>>(
                ff1bf, w2 + (size_t)l * 131072, b2 + l * 256, xbf, 256, 0,
                ln2_g + l * 256, ln2_b + l * 256, xbf,
                nullptr, nullptr, nullptr, 512);
        } else {
            gemm_ln_kernel<<<dim3(NRts / 32), 512, 0, stream>>>(
                ff1bf, w2 + (size_t)l * 131072, b2 + l * 256, xbf, 256, 0,
                ln2_g + l * 256, ln2_b + l * 256, nullptr,
                pred_W, pred_b, (float*)d_out, 512);
        }
    }
}

// Round 16
// 188.501 us; speedup vs baseline: 1.1036x; 1.1036x over previous
//
#include <hip/hip_runtime.h>
#include <hip/hip_bf16.h>
#include <cstddef>

// Shapes: B=16, M=128, L=512, HID=256, H=4, DH=64, LAYERS=2
#define Bsz 16
#define Msz 128
#define Lsz 512
#define HIDs 256

typedef __attribute__((ext_vector_type(4))) float f32x4;
typedef __attribute__((ext_vector_type(8))) __bf16 bf16x8;
typedef __attribute__((ext_vector_type(8))) unsigned short ushort8;

#define CHEB_K 12
#define PI_F 3.14159265358979323846f

static __device__ inline unsigned short f2bf(float f) {
    __hip_bfloat16 h = __float2bfloat16(f);
    return *(unsigned short*)&h;
}
static __device__ inline float bf2f(unsigned short u) {
    return __builtin_bit_cast(float, (unsigned)u << 16);
}
static __device__ inline void gload16(const ushort* g, ushort* l) {
    __builtin_amdgcn_global_load_lds(
        (const __attribute__((address_space(1))) void*)g,
        (__attribute__((address_space(3))) void*)l, 16, 0, 0);
}

// ---------------------------------------------------------------------------
// Chebyshev coefficients (1 block).
// ---------------------------------------------------------------------------
__global__ __launch_bounds__(256) void cheb_kernel(
    const float* __restrict__ kp, float* __restrict__ clut, float* __restrict__ cD)
{
    __shared__ float costab[CHEB_K][32];
    __shared__ float xq[32];
    __shared__ float alph[64];
    const int t = threadIdx.x;
    if (t < 64) {
        float p = kp[t];
        alph[t] = fmaxf(p, 0.f) + log1pf(__expf(-fabsf(p)));
    }
    #pragma unroll
    for (int i = 0; i < 2; i++) {
        int idx = i * 256 + t;
        if (idx < CHEB_K * 32) {
            int k = idx >> 5, q = idx & 31;
            float th = (q + 0.5f) * (PI_F / 32.f);
            costab[k][q] = __cosf((float)k * th);
        }
    }
    if (t < 32) xq[t] = 0.5f * (1.f + __cosf((t + 0.5f) * (PI_F / 32.f)));
    __syncthreads();

    if (t >= 192) return;
    const int d = t & 63, s1 = t >> 6;
    const float u = (float)(s1 + 1) * alph[d];
    float f[32];
    #pragma unroll
    for (int q = 0; q < 32; q++) f[q] = __expf(-u * xq[q]);
    #pragma unroll
    for (int k = 0; k < CHEB_K; k++) {
        float sum = 0.f;
        #pragma unroll
        for (int q = 0; q < 32; q++) sum = fmaf(f[q], costab[k][q], sum);
        float c = sum * ((k == 0 ? 1.f : 2.f) / 32.f);
        clut[s1 * (CHEB_K * 64) + k * 64 + d] = c;
        float sr = c;
        #pragma unroll
        for (int o = 1; o <= 32; o <<= 1) sr += __shfl_xor(sr, o, 64);
        if (d == 0) cD[s1 * CHEB_K + k] = sr;
    }
}

// ---------------------------------------------------------------------------
// Grid-fused prep: [0,1920) cvt/repack (Wqkv q-rows pre-scaled by 0.125);
// [1920,6016) tokenizer denominators; [6016] scaled bqkv copy.
// ---------------------------------------------------------------------------
__global__ __launch_bounds__(256) void prep_kernel(
    const float* __restrict__ ts_emb, const float* __restrict__ ct_emb,
    const float* __restrict__ ct_W, const float* __restrict__ fW0,
    const float* __restrict__ fW1, const float* __restrict__ fW2,
    const float* __restrict__ Wqkv, const float* __restrict__ Wo,
    const float* __restrict__ W1, const float* __restrict__ W2,
    ushort* __restrict__ Xcat, ushort* __restrict__ Wcat,
    ushort* __restrict__ cebin, ushort* __restrict__ wct,
    ushort* __restrict__ wf2, ushort* __restrict__ wqkv,
    ushort* __restrict__ wo, ushort* __restrict__ w1, ushort* __restrict__ w2,
    const float* __restrict__ ct_t, const float* __restrict__ ts_t,
    const float* __restrict__ cD, ushort* __restrict__ invW,
    const float* __restrict__ bqkv, float* __restrict__ bqs)
{
    const int bid = blockIdx.x;
    const int tid = threadIdx.x;

    if (bid < 1920) {
        const unsigned u = bid * 256u + tid;
        const float* src; ushort* dst; unsigned rel;
        float sc = 1.f;
        if (u < 262144u) {
            rel = u; src = ts_emb;
            dst = Xcat + ((size_t)(rel >> 5) * 512 + 256 + (rel & 31) * 8);
        } else if (u < 327680u) { rel = u - 262144u; src = ct_emb; dst = cebin + (size_t)rel * 8; }
        else if (u < 335872u) { rel = u - 327680u; src = ct_W; dst = wct + (size_t)rel * 8; }
        else if (u < 344064u) { rel = u - 335872u; src = fW0;
            dst = Wcat + ((size_t)(rel >> 5) * 512 + (rel & 31) * 8); }
        else if (u < 352256u) { rel = u - 344064u; src = fW1;
            dst = Wcat + ((size_t)(rel >> 5) * 512 + 256 + (rel & 31) * 8); }
        else if (u < 360448u) { rel = u - 352256u; src = fW2; dst = wf2 + (size_t)rel * 8; }
        else if (u < 409600u) { rel = u - 360448u; src = Wqkv; dst = wqkv + (size_t)rel * 8;
            if (((rel >> 5) % 768) < 256) sc = 0.125f; }   // q rows pre-scaled
        else if (u < 425984u) { rel = u - 409600u; src = Wo;  dst = wo + (size_t)rel * 8; }
        else if (u < 458752u) { rel = u - 425984u; src = W1;  dst = w1 + (size_t)rel * 8; }
        else                  { rel = u - 458752u; src = W2;  dst = w2 + (size_t)rel * 8; }
        float4 a = ((const float4*)src)[(size_t)rel * 2];
        float4 b = ((const float4*)src)[(size_t)rel * 2 + 1];
        ushort8 o;
        o[0] = f2bf(a.x * sc); o[1] = f2bf(a.y * sc); o[2] = f2bf(a.z * sc); o[3] = f2bf(a.w * sc);
        o[4] = f2bf(b.x * sc); o[5] = f2bf(b.y * sc); o[6] = f2bf(b.z * sc); o[7] = f2bf(b.w * sc);
        *(ushort8*)dst = o;
    } else if (bid < 6016) {
        __shared__ float cd[3][CHEB_K];
        if (tid < 3 * CHEB_K) cd[tid / CHEB_K][tid % CHEB_K] = cD[tid];
        __syncthreads();

        const unsigned G = (bid - 1920) * 256u + tid;
        const int b = G >> 16;
        const int n = (G >> 7) & 511;
        const int m = G & 127;

        float x = ct_t[b * Msz + m] - ts_t[b * Lsz + n];
        x = x * x;
        const float xi = 2.f * x - 1.f;
        const float xi2 = 2.f * xi;

        float t0 = 1.f, t1 = xi;
        float a1 = cd[0][0] + cd[0][1] * xi;
        float a2 = cd[1][0] + cd[1][1] * xi;
        float a3 = cd[2][0] + cd[2][1] * xi;
        #pragma unroll
        for (int k = 2; k < CHEB_K; k++) {
            float tn = fmaf(xi2, t1, -t0);
            a1 = fmaf(cd[0][k], tn, a1);
            a2 = fmaf(cd[1][k], tn, a2);
            a3 = fmaf(cd[2][k], tn, a3);
            t0 = t1; t1 = tn;
        }
        const size_t base = ((size_t)b * 3 * Lsz + n) * Msz + m;
        invW[base]                         = f2bf(1.f / a1);
        invW[base + (size_t)Lsz * Msz]     = f2bf(1.f / a2);
        invW[base + (size_t)2 * Lsz * Msz] = f2bf(1.f / a3);
    } else {
        #pragma unroll
        for (int i = 0; i < 6; i++) {
            int idx = i * 256 + tid;   // 1536 = 2*768
            int c = idx % 768;
            bqs[idx] = bqkv[idx] * ((c < 256) ? 0.125f : 1.f);
        }
    }
}

// ---------------------------------------------------------------------------
// MFMA bf16 GEMM, double-buffered LDS staging, 256 threads, 64x128 tile.
// ---------------------------------------------------------------------------
__global__ __launch_bounds__(256) void gemm_mfma_kernel(
    const ushort* __restrict__ X, const ushort* __restrict__ W,
    const float* __restrict__ bias, const float* __restrict__ bias2,
    ushort* __restrict__ Yb, int NR, int K, int OUT, int act)
{
    __shared__ ushort As[2][64 * 64];
    __shared__ ushort Bs[2][128 * 64];

    const int nbx = OUT >> 7;
    const int bx = blockIdx.x % nbx;
    const int by = blockIdx.x / nbx;
    const int r0 = by << 6, o0 = bx << 7;
    const int tid = threadIdx.x;
    const int w = tid >> 6;
    const int lane = tid & 63;
    const int wr = w >> 1, wc = w & 1;
    const int lr = lane & 15, lg = lane >> 4;

    const int grow = lane >> 3;
    const int gchunk = (lane & 7) ^ grow;

    unsigned aoff[2][2], boff[4][2];
    #pragma unroll
    for (int f = 0; f < 2; f++) {
        unsigned cc = (unsigned)((lg + 4 * f) ^ (lr & 7)) * 16u;
        #pragma unroll
        for (int m = 0; m < 2; m++)
            aoff[m][f] = (unsigned)(wr * 32 + m * 16 + lr) * 128u + cc;
        #pragma unroll
        for (int n = 0; n < 4; n++)
            boff[n][f] = (unsigned)(wc * 64 + n * 16 + lr) * 128u + cc;
    }

    f32x4 acc[2][4];
    #pragma unroll
    for (int m = 0; m < 2; m++)
        #pragma unroll
        for (int n = 0; n < 4; n++) acc[m][n] = (f32x4){0.f, 0.f, 0.f, 0.f};

    const int nk = K >> 6;

    auto stage = [&](int buf, int ks) {
        const int k0 = ks << 6;
        #pragma unroll
        for (int i = 0; i < 2; i++) {
            int row = w * 16 + i * 8 + grow;
            gload16(X + (size_t)(r0 + row) * K + k0 + gchunk * 8,
                    &As[buf][(w * 16 + i * 8) * 64]);
        }
        #pragma unroll
        for (int i = 0; i < 4; i++) {
            int row = w * 32 + i * 8 + grow;
            gload16(W + (size_t)(o0 + row) * K + k0 + gchunk * 8,
                    &Bs[buf][(w * 32 + i * 8) * 64]);
        }
    };

    stage(0, 0);
    __syncthreads();
    int cur = 0;
    for (int ks = 0; ks < nk; ks++) {
        if (ks + 1 < nk) stage(cur ^ 1, ks + 1);
        const char* Ab = (const char*)As[cur];
        const char* Bb = (const char*)Bs[cur];
        #pragma unroll
        for (int f = 0; f < 2; f++) {
            bf16x8 av[2], bv[4];
            #pragma unroll
            for (int m = 0; m < 2; m++)
                av[m] = *(const bf16x8*)(Ab + aoff[m][f]);
            #pragma unroll
            for (int n = 0; n < 4; n++)
                bv[n] = *(const bf16x8*)(Bb + boff[n][f]);
            #pragma unroll
            for (int m = 0; m < 2; m++)
                #pragma unroll
                for (int n = 0; n < 4; n++)
                    acc[m][n] = __builtin_amdgcn_mfma_f32_16x16x32_bf16(
                        av[m], bv[n], acc[m][n], 0, 0, 0);
        }
        __syncthreads();
        cur ^= 1;
    }

    const int ocol0 = o0 + wc * 64;
    float bn[4];
    #pragma unroll
    for (int n = 0; n < 4; n++) {
        int o = ocol0 + n * 16 + lr;
        bn[n] = bias[o] + (bias2 ? bias2[o] : 0.f);
    }

    #pragma unroll
    for (int m = 0; m < 2; m++) {
        #pragma unroll
        for (int p = 0; p < 4; p++) {
            int r = r0 + wr * 32 + m * 16 + 4 * lg + p;
            size_t rb = (size_t)r * OUT;
            #pragma unroll
            for (int n = 0; n < 4; n++) {
                int o = ocol0 + n * 16 + lr;
                float v = acc[m][n][p] + bn[n];
                if (act == 1)      v = (v > 0.f) ? v : (__expf(v) - 1.f);
                else if (act == 2) v = 0.5f * v * (1.f + erff(v * 0.70710678118654752f));
                Yb[rb + o] = f2bf(v);
            }
        }
    }
}

// ---------------------------------------------------------------------------
// Fused GEMM + residual(bf16) + LayerNorm (+ optional pred head).
// 512 threads = 8 waves (2 row-groups x 4 col-slices), 32 rows x 256 cols.
// ---------------------------------------------------------------------------
__global__ __launch_bounds__(512) void gemm_ln_kernel(
    const ushort* __restrict__ X, const ushort* __restrict__ W,
    const float* __restrict__ bias, const ushort* __restrict__ add,
    int addS, int addO,
    const float* __restrict__ lng, const float* __restrict__ lnb,
    ushort* __restrict__ Xb,
    const float* __restrict__ predW, const float* __restrict__ predb,
    float* __restrict__ pout, int K)
{
    __shared__ ushort As[2][32 * 64];
    __shared__ ushort Bs[2][256 * 64];
    __shared__ float redA[32][4];
    __shared__ float redB[32][4];

    const int r0 = blockIdx.x << 5;
    const int tid = threadIdx.x;
    const int w = tid >> 6;
    const int lane = tid & 63;
    const int lr = lane & 15, lg = lane >> 4;
    const int wg = w >> 2;
    const int ws = w & 3;
    const int grow = lane >> 3;
    const int gchunk = (lane & 7) ^ grow;

    unsigned aoff[2], boff[4][2];
    #pragma unroll
    for (int f = 0; f < 2; f++) {
        unsigned cc = (unsigned)((lg + 4 * f) ^ (lr & 7)) * 16u;
        aoff[f] = (unsigned)(wg * 16 + lr) * 128u + cc;
        #pragma unroll
        for (int n = 0; n < 4; n++)
            boff[n][f] = (unsigned)(ws * 64 + n * 16 + lr) * 128u + cc;
    }

    f32x4 acc[4];
    #pragma unroll
    for (int n = 0; n < 4; n++) acc[n] = (f32x4){0.f, 0.f, 0.f, 0.f};

    const int nk = K >> 6;

    auto stage = [&](int buf, int ks) {
        const int k0 = ks << 6;
        if (w < 4)
            gload16(X + (size_t)(r0 + w * 8 + grow) * K + k0 + gchunk * 8,
                    &As[buf][(w * 8) * 64]);
        #pragma unroll
        for (int i = 0; i < 4; i++) {
            gload16(W + (size_t)(w * 32 + i * 8 + grow) * K + k0 + gchunk * 8,
                    &Bs[buf][(w * 32 + i * 8) * 64]);
        }
    };

    stage(0, 0);
    __syncthreads();
    int cur = 0;
    for (int ks = 0; ks < nk; ks++) {
        if (ks + 1 < nk) stage(cur ^ 1, ks + 1);
        const char* Ab = (const char*)As[cur];
        const char* Bb = (const char*)Bs[cur];
        #pragma unroll
        for (int f = 0; f < 2; f++) {
            bf16x8 av = *(const bf16x8*)(Ab + aoff[f]);
            #pragma unroll
            for (int n = 0; n < 4; n++) {
                bf16x8 bv = *(const bf16x8*)(Bb + boff[n][f]);
                acc[n] = __builtin_amdgcn_mfma_f32_16x16x32_bf16(
                    av, bv, acc[n], 0, 0, 0);
            }
        }
        __syncthreads();
        cur ^= 1;
    }

    const int col0 = ws * 64;
    float bn[4], gv[4], bv2[4], pwv[4];
    #pragma unroll
    for (int n = 0; n < 4; n++) {
        int o = col0 + n * 16 + lr;
        bn[n] = bias[o];
        gv[n] = lng[o];
        bv2[n] = lnb[o];
        pwv[n] = predW ? predW[o] : 0.f;
    }
    #pragma unroll
    for (int p = 0; p < 4; p++) {
        size_t ra = (size_t)(r0 + wg * 16 + 4 * lg + p) * addS + addO;
        #pragma unroll
        for (int n = 0; n < 4; n++)
            acc[n][p] += bn[n] + bf2f(add[ra + col0 + n * 16 + lr]);
    }

    #pragma unroll
    for (int p = 0; p < 4; p++) {
        float s = acc[0][p] + acc[1][p] + acc[2][p] + acc[3][p];
        #pragma unroll
        for (int o = 1; o <= 8; o <<= 1) s += __shfl_xor(s, o);
        if (lr == 0) redA[wg * 16 + 4 * lg + p][ws] = s;
    }
    __syncthreads();
    float mu[4];
    #pragma unroll
    for (int p = 0; p < 4; p++) {
        int row = wg * 16 + 4 * lg + p;
        mu[p] = (redA[row][0] + redA[row][1] + redA[row][2] + redA[row][3]) * (1.f / 256.f);
    }

    #pragma unroll
    for (int p = 0; p < 4; p++) {
        float q = 0.f;
        #pragma unroll
        for (int n = 0; n < 4; n++) {
            float dl = acc[n][p] - mu[p];
            q = fmaf(dl, dl, q);
        }
        #pragma unroll
        for (int o = 1; o <= 8; o <<= 1) q += __shfl_xor(q, o);
        if (lr == 0) redB[wg * 16 + 4 * lg + p][ws] = q;
    }
    __syncthreads();

    #pragma unroll
    for (int p = 0; p < 4; p++) {
        int row = wg * 16 + 4 * lg + p;
        float var = (redB[row][0] + redB[row][1] + redB[row][2] + redB[row][3]) * (1.f / 256.f);
        float rsig = rsqrtf(var + 1e-5f);
        size_t rb = (size_t)(r0 + row) * 256;
        float pd = 0.f;
        #pragma unroll
        for (int n = 0; n < 4; n++) {
            int o = col0 + n * 16 + lr;
            float xn = (acc[n][p] - mu[p]) * rsig * gv[n] + bv2[n];
            if (Xb) Xb[rb + o] = f2bf(xn);
            pd = fmaf(xn, pwv[n], pd);
        }
        if (predW) {
            #pragma unroll
            for (int o = 1; o <= 8; o <<= 1) pd += __shfl_xor(pd, o);
            if (lr == 0) redA[row][ws] = pd;
        }
    }
    if (predW) {
        __syncthreads();
        if (tid < 32)
            pout[r0 + tid] = redA[tid][0] + redA[tid][1] + redA[tid][2]
                           + redA[tid][3] + predb[0];
    }
}

// ---------------------------------------------------------------------------
// Grid-fused tokenizer: [0,384) tok3 MFMA; [384,400) scale-0 broadcast.
// ---------------------------------------------------------------------------
__global__ __launch_bounds__(256) void tokmix_kernel(
    const float* __restrict__ ct_t, const float* __restrict__ ts_t,
    const ushort* __restrict__ ceb, const ushort* __restrict__ invW,
    const float* __restrict__ clut, ushort* __restrict__ Xcat)
{
    const int bid = blockIdx.x;
    const int tid = threadIdx.x;

    if (bid < 384) {
        const int nt = bid & 7;
        const int s1 = (bid >> 3) % 3;
        const int b  = bid / 24;
        const int w = tid >> 6, lane = tid & 63, g = lane >> 4, r = lane & 15;

        __shared__ ushort ceT[64][136];
        __shared__ float  cl[CHEB_K][64];
        __shared__ float  cts[128];

        #pragma unroll
        for (int i = 0; i < 8; i++) {
            int idx = i * 256 + tid;
            int m = idx >> 4, d4 = (idx & 15) << 2;
            const ushort* gp = ceb + (((size_t)b * 128 + m) << 8) + (s1 + 1) * 64 + d4;
            ushort4 v = *(const ushort4*)gp;
            ceT[d4 + 0][m] = v.x; ceT[d4 + 1][m] = v.y;
            ceT[d4 + 2][m] = v.z; ceT[d4 + 3][m] = v.w;
        }
        #pragma unroll
        for (int i = 0; i < 3; i++) {
            int idx = i * 256 + tid;
            cl[idx >> 6][idx & 63] = clut[s1 * (CHEB_K * 64) + idx];
        }
        if (tid < 128) cts[tid] = ct_t[b * 128 + tid];
        __syncthreads();

        const int nrow = nt * 64 + w * 16 + r;
        const float tsn = ts_t[b * 512 + nrow];

        float xi2v[4][8], Ta[4][8], Tb[4][8];
        #pragma unroll
        for (int t4 = 0; t4 < 4; t4++) {
            int m0 = 8 * g + 32 * t4;
            ushort8 iv = *(const ushort8*)&invW[((((size_t)b * 3 + s1) * 512 + nrow) << 7) + m0];
            #pragma unroll
            for (int j = 0; j < 8; j++) {
                float dfx = cts[m0 + j] - tsn;
                float x = dfx * dfx;
                float xi = 2.f * x - 1.f;
                float w0 = bf2f(iv[j]);
                xi2v[t4][j] = 2.f * xi;
                Ta[t4][j] = w0;
                Tb[t4][j] = w0 * xi;
            }
        }

        bf16x8 cef[4][4];
        #pragma unroll
        for (int db = 0; db < 4; db++)
            #pragma unroll
            for (int t4 = 0; t4 < 4; t4++)
                cef[db][t4] = *(const bf16x8*)&ceT[db * 16 + r][8 * g + 32 * t4];

        f32x4 acc[4];
        #pragma unroll
        for (int db = 0; db < 4; db++) acc[db] = (f32x4){0.f, 0.f, 0.f, 0.f};

        #pragma unroll
        for (int k = 0; k < CHEB_K; k++) {
            if (k >= 2) {
                #pragma unroll
                for (int t4 = 0; t4 < 4; t4++)
                    #pragma unroll
                    for (int j = 0; j < 8; j++) {
                        if (k & 1) Tb[t4][j] = fmaf(xi2v[t4][j], Ta[t4][j], -Tb[t4][j]);
                        else       Ta[t4][j] = fmaf(xi2v[t4][j], Tb[t4][j], -Ta[t4][j]);
                    }
            }
            bf16x8 af[4];
            #pragma unroll
            for (int t4 = 0; t4 < 4; t4++) {
                ushort8 u;
                #pragma unroll
                for (int j = 0; j < 8; j++)
                    u[j] = f2bf((k & 1) ? Tb[t4][j] : Ta[t4][j]);
                af[t4] = __builtin_bit_cast(bf16x8, u);
            }
            #pragma unroll
            for (int db = 0; db < 4; db++) {
                f32x4 gk = (f32x4){0.f, 0.f, 0.f, 0.f};
                #pragma unroll
                for (int t4 = 0; t4 < 4; t4++)
                    gk = __builtin_amdgcn_mfma_f32_16x16x32_bf16(af[t4], cef[db][t4], gk, 0, 0, 0);
                float ck = cl[k][db * 16 + r];
                #pragma unroll
                for (int p = 0; p < 4; p++) acc[db][p] = fmaf(ck, gk[p], acc[db][p]);
            }
        }

        #pragma unroll
        for (int db = 0; db < 4; db++)
            #pragma unroll
            for (int p = 0; p < 4; p++) {
                int n_out = nt * 64 + w * 16 + 4 * g + p;
                Xcat[((size_t)b * 512 + n_out) * 512 + (s1 + 1) * 64 + db * 16 + r] =
                    f2bf(acc[db][p]);
            }
    } else {
        const int b = bid - 384;
        const int d = tid & 63, q = tid >> 6;
        float s = 0.f;
        #pragma unroll 8
        for (int i = 0; i < 32; i++) {
            int m = q * 32 + i;
            s += bf2f(ceb[(((size_t)b * 128 + m) << 8) + d]);
        }
        __shared__ float red0[4][64];
        __shared__ ushort row0[64];
        red0[q][d] = s;
        __syncthreads();
        if (tid < 64)
            row0[tid] = f2bf((red0[0][tid] + red0[1][tid] + red0[2][tid] + red0[3][tid])
                             * (1.f / 64.f));
        __syncthreads();
        #pragma unroll
        for (int i = 0; i < 16; i++) {
            int idx = i * 256 + tid;
            int n = idx >> 3, j = idx & 7;
            *(ushort8*)&Xcat[((size_t)b * 512 + n) * 512 + j * 8] =
                *(const ushort8*)&row0[j * 8];
        }
    }
}

// ---------------------------------------------------------------------------
// MFMA bf16 flash attention (q pre-scaled by 0.125 upstream).
// 256 threads, 128-key chunks, single LDS buffer + register prefetch,
// setprio around MFMA clusters. P stored in LDS as bf16 (direct A-frag reads).
// Grid = B*H*8 = 512.
// ---------------------------------------------------------------------------
__global__ __launch_bounds__(256) void attn_mfma_kernel(
    const ushort* __restrict__ qkv, ushort* __restrict__ Ob)
{
    const int bid = blockIdx.x;
    const int qt = bid & 7;
    const int h  = (bid >> 3) & 3;
    const int b  = bid >> 5;
    const int t  = threadIdx.x;
    const int w  = t >> 6;
    const int lane = t & 63;
    const int g = lane >> 4;
    const int r = lane & 15;

    __shared__ ushort Ks[128][72];
    __shared__ ushort Vt[64][136];     // [d][k]
    __shared__ ushort Pb[4][16][136];  // bf16 P, row pitch 272B (16B-aligned)

    const ushort* base = qkv + (size_t)b * Lsz * 768;
    const int q0 = qt * 64 + w * 16;

    bf16x8 qf[2];
    {
        const ushort* qp = base + (size_t)(q0 + r) * 768 + h * 64 + 8 * g;
        qf[0] = __builtin_bit_cast(bf16x8, *(const ushort8*)qp);
        qf[1] = __builtin_bit_cast(bf16x8, *(const ushort8*)(qp + 32));
    }

    f32x4 Ofr[4];
    #pragma unroll
    for (int dblk = 0; dblk < 4; dblk++) Ofr[dblk] = (f32x4){0.f, 0.f, 0.f, 0.f};
    float m_run[4] = {-1e30f, -1e30f, -1e30f, -1e30f};
    float l_run[4] = {0.f, 0.f, 0.f, 0.f};

    const int srow = t >> 1;        // 0..127
    const int sseg = t & 1;         // 0..1  (32 ushorts each)

    ushort8 pk[4], pv[4];
    auto gload_chunk = [&](int c) {
        const ushort* kr = base + (size_t)(c * 128 + srow) * 768 + 256 + h * 64 + sseg * 32;
        #pragma unroll
        for (int i = 0; i < 4; i++) {
            pk[i] = *(const ushort8*)(kr + 8 * i);
            pv[i] = *(const ushort8*)(kr + 256 + 8 * i);
        }
    };
    auto write_chunk = [&]() {
        #pragma unroll
        for (int i = 0; i < 4; i++) {
            *(ushort8*)&Ks[srow][sseg * 32 + 8 * i] = pk[i];
            #pragma unroll
            for (int j = 0; j < 8; j++)
                Vt[sseg * 32 + 8 * i + j][srow] = pv[i][j];
        }
    };

    gload_chunk(0);
    write_chunk();
    __syncthreads();

    for (int c = 0; c < 4; c++) {
        if (c < 3) gload_chunk(c + 1);   // loads in flight over compute

        // ---- S = Q K^T (q pre-scaled) ----
        f32x4 sfr[8];
        __builtin_amdgcn_s_setprio(1);
        #pragma unroll
        for (int s = 0; s < 8; s++) {
            f32x4 a2 = (f32x4){0.f, 0.f, 0.f, 0.f};
            #pragma unroll
            for (int f = 0; f < 2; f++) {
                bf16x8 kf = *(const bf16x8*)&Ks[s * 16 + r][8 * g + 32 * f];
                a2 = __builtin_amdgcn_mfma_f32_16x16x32_bf16(qf[f], kf, a2, 0, 0, 0);
            }
            sfr[s] = a2;
        }
        __builtin_amdgcn_s_setprio(0);

        // ---- online softmax; P written to LDS directly as bf16 ----
        #pragma unroll
        for (int p = 0; p < 4; p++) {
            float rm = sfr[0][p];
            #pragma unroll
            for (int s = 1; s < 8; s++) rm = fmaxf(rm, sfr[s][p]);
            #pragma unroll
            for (int o = 1; o <= 8; o <<= 1) rm = fmaxf(rm, __shfl_xor(rm, o));
            float mnew = fmaxf(m_run[p], rm);
            float sc = __expf(m_run[p] - mnew);
            m_run[p] = mnew;
            float rs = 0.f;
            #pragma unroll
            for (int s = 0; s < 8; s++) {
                float pvx = __expf(sfr[s][p] - mnew);
                Pb[w][4 * g + p][s * 16 + r] = f2bf(pvx);
                rs += pvx;
            }
            #pragma unroll
            for (int o = 1; o <= 8; o <<= 1) rs += __shfl_xor(rs, o);
            l_run[p] = l_run[p] * sc + rs;
            #pragma unroll
            for (int dblk = 0; dblk < 4; dblk++) Ofr[dblk][p] *= sc;
        }

        __asm__ volatile("s_waitcnt lgkmcnt(0)" ::: "memory");

        // ---- O += P @ V  (P A-frags read directly as bf16x8) ----
        #pragma unroll
        for (int ks2 = 0; ks2 < 4; ks2++) {
            bf16x8 pa = *(const bf16x8*)&Pb[w][r][8 * g + 32 * ks2];
            __builtin_amdgcn_s_setprio(1);
            #pragma unroll
            for (int dblk = 0; dblk < 4; dblk++) {
                bf16x8 vb = *(const bf16x8*)&Vt[dblk * 16 + r][32 * ks2 + 8 * g];
                Ofr[dblk] = __builtin_amdgcn_mfma_f32_16x16x32_bf16(
                    pa, vb, Ofr[dblk], 0, 0, 0);
            }
            __builtin_amdgcn_s_setprio(0);
        }

        __syncthreads();                 // all waves done reading Ks/Vt
        if (c < 3) {
            write_chunk();
            __syncthreads();             // writes visible
        }
    }

    #pragma unroll
    for (int dblk = 0; dblk < 4; dblk++) {
        #pragma unroll
        for (int p = 0; p < 4; p++) {
            int row = q0 + 4 * g + p;
            Ob[(size_t)(b * Lsz + row) * HIDs + h * 64 + dblk * 16 + r] =
                f2bf(Ofr[dblk][p] / l_run[p]);
        }
    }
}

// ---------------------------------------------------------------------------
extern "C" void kernel_launch(void* const* d_in, const int* in_sizes, int n_in,
                              void* d_out, int out_size, void* d_ws, size_t ws_size,
                              hipStream_t stream)
{
    (void)in_sizes; (void)n_in; (void)out_size; (void)ws_size;

    const float* ct_t   = (const float*)d_in[0];
    const float* ts_t   = (const float*)d_in[1];
    const float* ct_emb = (const float*)d_in[2];
    const float* ts_emb = (const float*)d_in[3];
    const float* kp     = (const float*)d_in[4];
    const float* ct_W   = (const float*)d_in[5];
    const float* ct_b   = (const float*)d_in[6];
    const float* fW0    = (const float*)d_in[7];
    const float* fb0    = (const float*)d_in[8];
    const float* fW1    = (const float*)d_in[9];
    const float* fb1    = (const float*)d_in[10];
    const float* fW2    = (const float*)d_in[11];
    const float* fb2    = (const float*)d_in[12];
    const float* f_ln_g = (const float*)d_in[13];
    const float* f_ln_b = (const float*)d_in[14];
    const float* Wqkv   = (const float*)d_in[15];
    const float* bqkv   = (const float*)d_in[16];
    const float* Wo     = (const float*)d_in[17];
    const float* bo     = (const float*)d_in[18];
    const float* W1     = (const float*)d_in[19];
    const float* b1     = (const float*)d_in[20];
    const float* W2     = (const float*)d_in[21];
    const float* b2     = (const float*)d_in[22];
    const float* ln1_g  = (const float*)d_in[23];
    const float* ln1_b  = (const float*)d_in[24];
    const float* ln2_g  = (const float*)d_in[25];
    const float* ln2_b  = (const float*)d_in[26];
    const float* pred_W = (const float*)d_in[27];
    const float* pred_b = (const float*)d_in[28];

    // ---- workspace layout (ushort units unless noted) ----
    ushort* wsb = (ushort*)d_ws;
    ushort* invW  = wsb;                    // [0, 12582912)
    ushort* auxbf = wsb;                    //   reuse after tokmix
    ushort* qkvbf = wsb;                    //   reuse
    ushort* ff1bf = wsb;                    //   reuse
    ushort* Xcat  = wsb + 12582912;         // 4,194,304  [8192][512]
    ushort* Wcat  = wsb + 16777216;         // 131,072
    ushort* cebin = wsb + 16908288;         // 524,288
    ushort* cebout= wsb + 17432576;         // 524,288
    ushort* wct   = wsb + 17956864;         // 65,536
    ushort* wf2   = wsb + 18022400;         // 65,536
    ushort* wqkv  = wsb + 18087936;         // 393,216
    ushort* wo    = wsb + 18481152;         // 131,072
    ushort* w1    = wsb + 18612224;         // 262,144
    ushort* w2    = wsb + 18874368;         // 262,144 -> ends 19,136,512
    ushort* xbf   = wsb + 19136512;         // 2,097,152
    ushort* obf   = wsb + 21233664;         // 2,097,152 -> ends 23,330,816
    float*  wsf   = (float*)d_ws;
    float*  clut  = wsf + 11665408;         // 2,304 fl
    float*  cDp   = wsf + 11667712;         // 36 fl
    float*  bqs   = wsf + 11667776;         // 1,536 fl

    const int NRts = Bsz * Lsz;  // 8192
    const int NRct = Bsz * Msz;  // 2048
    auto grid = [](int nr, int out) { return dim3((unsigned)((nr >> 6) * (out >> 7))); };

    // --- prep: cheb (1 blk), then cvt + denom3 + bq scale grid-fused ---
    cheb_kernel<<<dim3(1), 256, 0, stream>>>(kp, clut, cDp);
    prep_kernel<<<dim3(1920 + 4096 + 1), 256, 0, stream>>>(
        ts_emb, ct_emb, ct_W, fW0, fW1, fW2, Wqkv, Wo, W1, W2,
        Xcat, Wcat, cebin, wct, wf2, wqkv, wo, w1, w2,
        ct_t, ts_t, cDp, invW, bqkv, bqs);

    // --- tokenizer ---
    gemm_mfma_kernel<<<grid(NRct, 256), 256, 0, stream>>>(
        cebin, wct, ct_b, nullptr, cebout, NRct, 256, 256, 0);
    tokmix_kernel<<<dim3(400), 256, 0, stream>>>(ct_t, ts_t, cebout, invW, clut, Xcat);

    // --- fusion: aux = ELU(Xcat@Wcat + fb0+fb1); x = LN(aux@fW2^T + fb2 + ts_emb) ---
    gemm_mfma_kernel<<<grid(NRts, 256), 256, 0, stream>>>(
        Xcat, Wcat, fb0, fb1, auxbf, NRts, 512, 256, 1);
    gemm_ln_kernel<<<dim3(NRts / 32), 512, 0, stream>>>(
        auxbf, wf2, fb2, Xcat, 512, 256, f_ln_g, f_ln_b, xbf,
        nullptr, nullptr, nullptr, 256);

    // --- transformer layers ---
    for (int l = 0; l < 2; l++) {
        gemm_mfma_kernel<<<grid(NRts, 768), 256, 0, stream>>>(
            xbf, wqkv + (size_t)l * 196608, bqs + l * 768, nullptr,
            qkvbf, NRts, 256, 768, 0);
        attn_mfma_kernel<<<dim3(512), 256, 0, stream>>>(qkvbf, obf);
        gemm_ln_kernel<<<dim3(NRts / 32), 512, 0, stream>>>(
            obf, wo + (size_t)l * 65536, bo + l * 256, xbf, 256, 0,
            ln1_g + l * 256, ln1_b + l * 256, xbf,
            nullptr, nullptr, nullptr, 256);
        gemm_mfma_kernel<<<grid(NRts, 512), 256, 0, stream>>>(
            xbf, w1 + (size_t)l * 131072, b1 + l * 512, nullptr,
            ff1bf, NRts, 256, 512, 2);
        if (l == 0) {
            gemm_ln_kernel<<<dim3(NRts / 32), 512, 0, stream>>>(
                ff1bf, w2 + (size_t)l * 131072, b2 + l * 256, xbf, 256, 0,
                ln2_g + l * 256, ln2_b + l * 256, xbf,
                nullptr, nullptr, nullptr, 512);
        } else {
            gemm_ln_kernel<<<dim3(NRts / 32), 512, 0, stream>>>(
                ff1bf, w2 + (size_t)l * 131072, b2 + l * 256, xbf, 256, 0,
                ln2_g + l * 256, ln2_b + l * 256, nullptr,
                pred_W, pred_b, (float*)d_out, 512);
        }
    }
}